// Round 1
// baseline (911.398 us; speedup 1.0000x reference)
//
#include <hip/hip_runtime.h>
#include <cstddef>

#define NB 4
#define ND 512
#define NT 4096
#define NK 4096
#define NBT (NB * NT)

#define TM 64
#define TN 128
#define BD 32
#define KSPLIT 2
#define KCHUNK (NK / KSPLIT)

// ---------------------------------------------------------------- enorm ----
__global__ void enorm_kernel(const float* __restrict__ emb,
                             float* __restrict__ enorm) {
  int row = blockIdx.x * 4 + (threadIdx.x >> 6);
  int lane = threadIdx.x & 63;
  const float* e = emb + (size_t)row * ND;
  float s = 0.f;
#pragma unroll
  for (int i = 0; i < ND / 64; ++i) {
    float v = e[lane + i * 64];
    s += v * v;
  }
#pragma unroll
  for (int m = 32; m; m >>= 1) s += __shfl_xor(s, m);
  if (lane == 0) enorm[row] = s;
}

// --------------------------------------------------------------- argmin ----
// scores[bt, k] = ||e_k||^2 - 2 * dot(x_bt, e_k); running argmin over k.
// Grid: (NBT/TM, KSPLIT). Block: 256. Each thread: 4 rows x 8 cols.
__global__ __launch_bounds__(256) void argmin_kernel(
    const float* __restrict__ x, const float* __restrict__ emb,
    const float* __restrict__ enorm, float* __restrict__ cand_v,
    int* __restrict__ cand_i) {
  __shared__ float xs[BD][TM];      // [d][t]
  __shared__ float es[BD][TN + 4];  // [d][k], padded
  const int tid = threadIdx.x;
  const int bt0 = blockIdx.x * TM;
  const int b = bt0 / NT;
  const int t0 = bt0 % NT;
  const float* xb = x + (size_t)b * ND * NT + t0;
  const int tx = tid & 15, ty = tid >> 4;
  const int kbase = blockIdx.y * KCHUNK;

  float runv[4];
  int runi[4];
#pragma unroll
  for (int i = 0; i < 4; ++i) {
    runv[i] = INFINITY;
    runi[i] = 0;
  }

  for (int k0 = kbase; k0 < kbase + KCHUNK; k0 += TN) {
    float acc[4][8];
#pragma unroll
    for (int i = 0; i < 4; ++i)
#pragma unroll
      for (int j = 0; j < 8; ++j) acc[i][j] = 0.f;

    for (int d0 = 0; d0 < ND; d0 += BD) {
      __syncthreads();
      {  // stage x tile: coalesced along t
        const int tt = tx * 4;
        const int dd = ty;
        *(float4*)&xs[dd][tt] =
            *(const float4*)&xb[(size_t)(d0 + dd) * NT + tt];
        *(float4*)&xs[dd + 16][tt] =
            *(const float4*)&xb[(size_t)(d0 + dd + 16) * NT + tt];
      }
      {  // stage e tile transposed: coalesced along d, scatter into [d][k]
        const int dd4 = (tid & 7) * 4;
        const int kkb = tid >> 3;
#pragma unroll
        for (int r = 0; r < 4; ++r) {
          const int kk = kkb + r * 32;
          float4 v = *(const float4*)&emb[(size_t)(k0 + kk) * ND + d0 + dd4];
          es[dd4 + 0][kk] = v.x;
          es[dd4 + 1][kk] = v.y;
          es[dd4 + 2][kk] = v.z;
          es[dd4 + 3][kk] = v.w;
        }
      }
      __syncthreads();
#pragma unroll
      for (int dd = 0; dd < BD; ++dd) {
        const float4 xv = *(const float4*)&xs[dd][ty * 4];
        const float4 ea = *(const float4*)&es[dd][tx * 4];
        const float4 eb = *(const float4*)&es[dd][64 + tx * 4];
        const float xa[4] = {xv.x, xv.y, xv.z, xv.w};
        const float ee[8] = {ea.x, ea.y, ea.z, ea.w, eb.x, eb.y, eb.z, eb.w};
#pragma unroll
        for (int i = 0; i < 4; ++i)
#pragma unroll
          for (int j = 0; j < 8; ++j) acc[i][j] += xa[i] * ee[j];
      }
    }
#pragma unroll
    for (int j = 0; j < 8; ++j) {
      const int c = k0 + (j < 4 ? tx * 4 + j : 64 + tx * 4 + j - 4);
      const float en = enorm[c];
#pragma unroll
      for (int i = 0; i < 4; ++i) {
        const float sc = en - 2.f * acc[i][j];
        if (sc < runv[i]) {  // strict <, ascending c => first-min tie-break
          runv[i] = sc;
          runi[i] = c;
        }
      }
    }
  }
  // reduce across the 16 col-group lanes (lane bits 0..3)
#pragma unroll
  for (int m = 1; m < 16; m <<= 1) {
#pragma unroll
    for (int i = 0; i < 4; ++i) {
      const float ov = __shfl_xor(runv[i], m);
      const int oi = __shfl_xor(runi[i], m);
      if (ov < runv[i] || (ov == runv[i] && oi < runi[i])) {
        runv[i] = ov;
        runi[i] = oi;
      }
    }
  }
  if (tx == 0) {
#pragma unroll
    for (int i = 0; i < 4; ++i) {
      const int row = bt0 + ty * 4 + i;
      cand_v[blockIdx.y * NBT + row] = runv[i];
      cand_i[blockIdx.y * NBT + row] = runi[i];
    }
  }
}

// -------------------------------------------------------------- combine ----
__global__ void combine_kernel(const float* __restrict__ cv,
                               const int* __restrict__ ci,
                               int* __restrict__ idx_ws,
                               float* __restrict__ idxf) {
  int r = blockIdx.x * 256 + threadIdx.x;
  float v0 = cv[r], v1 = cv[NBT + r];
  int i0 = ci[r], i1 = ci[NBT + r];
  int best = (v1 < v0 || (v1 == v0 && i1 < i0)) ? i1 : i0;
  idx_ws[r] = best;
  idxf[r] = (float)best;
}

// ------------------------------------------------------- gather + loss -----
// Grid: (NBT/64, ND/64). Block 256. LDS transpose tile.
__global__ __launch_bounds__(256) void gather_kernel(
    const float* __restrict__ x, const float* __restrict__ emb,
    const int* __restrict__ idx_ws, float* __restrict__ vals_out,
    float* __restrict__ partials) {
  __shared__ float tile[64][65];
  const int tid = threadIdx.x;
  const int bt0 = blockIdx.x * 64;
  const int d0 = blockIdx.y * 64;
  const int b = bt0 / NT;
  const int t0 = bt0 % NT;

  {  // load embedding rows (coalesced along d) into [t][d] tile
    const int dd4 = (tid & 15) * 4;
    const int ttb = tid >> 4;
#pragma unroll
    for (int p = 0; p < 4; ++p) {
      const int tt = ttb + p * 16;
      const int r = idx_ws[bt0 + tt];
      float4 v = *(const float4*)&emb[(size_t)r * ND + d0 + dd4];
      tile[tt][dd4 + 0] = v.x;
      tile[tt][dd4 + 1] = v.y;
      tile[tt][dd4 + 2] = v.z;
      tile[tt][dd4 + 3] = v.w;
    }
  }
  __syncthreads();
  float lsum = 0.f;
  {  // write out [B,D,T] (coalesced along t) + fused loss accumulation
    const int tt4 = (tid & 15) * 4;
    const int ddb = tid >> 4;
#pragma unroll
    for (int p = 0; p < 4; ++p) {
      const int dd = ddb + p * 16;
      float4 v;
      v.x = tile[tt4 + 0][dd];
      v.y = tile[tt4 + 1][dd];
      v.z = tile[tt4 + 2][dd];
      v.w = tile[tt4 + 3][dd];
      const size_t o = (size_t)b * ND * NT + (size_t)(d0 + dd) * NT + t0 + tt4;
      const float4 xr = *(const float4*)&x[o];
      *(float4*)&vals_out[o] = v;
      const float e0 = xr.x - v.x, e1 = xr.y - v.y;
      const float e2 = xr.z - v.z, e3 = xr.w - v.w;
      lsum += e0 * e0 + e1 * e1 + e2 * e2 + e3 * e3;
    }
  }
#pragma unroll
  for (int m = 32; m; m >>= 1) lsum += __shfl_xor(lsum, m);
  __shared__ float wsum[4];
  if ((tid & 63) == 0) wsum[tid >> 6] = lsum;
  __syncthreads();
  if (tid == 0)
    partials[blockIdx.y * gridDim.x + blockIdx.x] =
        wsum[0] + wsum[1] + wsum[2] + wsum[3];
}

// ----------------------------------------------------------------- loss ----
__global__ void loss_kernel(const float* __restrict__ partials, int n,
                            float* __restrict__ out) {
  float s = 0.f;
  for (int i = threadIdx.x; i < n; i += 256) s += partials[i];
#pragma unroll
  for (int m = 32; m; m >>= 1) s += __shfl_xor(s, m);
  __shared__ float wsum[4];
  if ((threadIdx.x & 63) == 0) wsum[threadIdx.x >> 6] = s;
  __syncthreads();
  if (threadIdx.x == 0)
    out[0] = 2.0f * (wsum[0] + wsum[1] + wsum[2] + wsum[3]) /
             (float)((size_t)NB * ND * NT);
}

// --------------------------------------------------------------- launch ----
extern "C" void kernel_launch(void* const* d_in, const int* in_sizes, int n_in,
                              void* d_out, int out_size, void* d_ws,
                              size_t ws_size, hipStream_t stream) {
  const float* x = (const float*)d_in[0];
  const float* emb = (const float*)d_in[1];
  float* out = (float*)d_out;
  float* vals_out = out;                              // [B, D, T]
  float* idxf_out = out + (size_t)NB * ND * NT;       // [B, T] as float
  float* loss_out = idxf_out + NBT;                   // scalar

  float* enorm = (float*)d_ws;                        // NK
  float* cand_v = enorm + NK;                         // KSPLIT * NBT
  int* cand_i = (int*)(cand_v + KSPLIT * NBT);        // KSPLIT * NBT
  int* idx_ws = cand_i + KSPLIT * NBT;                // NBT
  float* partials = (float*)(idx_ws + NBT);           // (NBT/64)*(ND/64)

  enorm_kernel<<<NK / 4, 256, 0, stream>>>(emb, enorm);
  dim3 ag(NBT / TM, KSPLIT);
  argmin_kernel<<<ag, 256, 0, stream>>>(x, emb, enorm, cand_v, cand_i);
  combine_kernel<<<NBT / 256, 256, 0, stream>>>(cand_v, cand_i, idx_ws,
                                                idxf_out);
  dim3 gg(NBT / 64, ND / 64);
  gather_kernel<<<gg, 256, 0, stream>>>(x, emb, idx_ws, vals_out, partials);
  loss_kernel<<<1, 256, 0, stream>>>(partials, (NBT / 64) * (ND / 64),
                                     loss_out);
}

// Round 2
// 424.139 us; speedup vs baseline: 2.1488x; 2.1488x over previous
//
#include <hip/hip_runtime.h>
#include <cstddef>
#include <cstdint>

#define NB 4
#define ND 512
#define NT 4096
#define NK 4096
#define NBT (NB * NT)
#define KP 1536  // augmented K' = 3*ND (xh*eh + xh*el + xl*eh)

#define BM 128
#define BN 128
#define BK 64

typedef __attribute__((ext_vector_type(4))) float f32x4;
typedef __attribute__((ext_vector_type(8))) short short8;
typedef __attribute__((ext_vector_type(8))) unsigned short u16x8;
typedef unsigned short u16;

__device__ inline u16 f2bf_rn(float f) {  // round-to-nearest-even bf16
  unsigned u = __float_as_uint(f);
  return (u16)((u + 0x7FFFu + ((u >> 16) & 1u)) >> 16);
}
__device__ inline float bf2f(u16 h) {
  return __uint_as_float(((unsigned)h) << 16);
}
__device__ inline void gload16(void* lds, const void* g) {
  __builtin_amdgcn_global_load_lds(
      (const __attribute__((address_space(1))) unsigned int*)g,
      (__attribute__((address_space(3))) unsigned int*)lds, 16, 0, 0);
}

// ---------------------------------------------------- e conversion + norm --
// eh2 = bf16(2e), el2 = bf16(2e - eh2)  (x2 exact in bf16); enorm = ||e||^2
__global__ void conv_e_kernel(const float* __restrict__ emb,
                              u16* __restrict__ eh2, u16* __restrict__ el2,
                              float* __restrict__ enorm) {
  int row = blockIdx.x * 4 + (threadIdx.x >> 6);
  int l = threadIdx.x & 63;
  const float* e = emb + (size_t)row * ND;
  float s = 0.f;
#pragma unroll
  for (int i = 0; i < ND / 64; ++i) {
    int idx = l + i * 64;
    float v = e[idx];
    s += v * v;
    float v2 = 2.f * v;
    u16 h = f2bf_rn(v2);
    u16 lo = f2bf_rn(v2 - bf2f(h));
    eh2[(size_t)row * ND + idx] = h;
    el2[(size_t)row * ND + idx] = lo;
  }
#pragma unroll
  for (int m = 32; m; m >>= 1) s += __shfl_xor(s, m);
  if (l == 0) enorm[row] = s;
}

// ------------------------------------------- x conversion (+ transpose) ----
// x [B,D,T] fp32 -> xh/xl [B*T, D] bf16 hi/lo
__global__ __launch_bounds__(256) void conv_x_kernel(const float* __restrict__ x,
                                                     u16* __restrict__ xh,
                                                     u16* __restrict__ xl) {
  __shared__ float tile[64][68];
  const int tid = threadIdx.x;
  const int bt0 = blockIdx.x * 64, d0 = blockIdx.y * 64;
  const int b = bt0 / NT, t0 = bt0 % NT;
  const float* xb = x + (size_t)b * ND * NT;
  {
    const int tt4 = (tid & 15) * 4, ddb = tid >> 4;
#pragma unroll
    for (int p = 0; p < 4; ++p) {
      const int dd = ddb + p * 16;
      float4 v = *(const float4*)&xb[(size_t)(d0 + dd) * NT + t0 + tt4];
      *(float4*)&tile[dd][tt4] = v;
    }
  }
  __syncthreads();
  {
    const int t_loc = tid >> 2, dg = tid & 3;
    u16 hs[16], ls[16];
#pragma unroll
    for (int j = 0; j < 16; ++j) {
      float f = tile[dg * 16 + j][t_loc];
      u16 h = f2bf_rn(f);
      hs[j] = h;
      ls[j] = f2bf_rn(f - bf2f(h));
    }
    const size_t base = (size_t)(bt0 + t_loc) * ND + d0 + dg * 16;
    *(u16x8*)&xh[base] = *(const u16x8*)&hs[0];
    *(u16x8*)&xh[base + 8] = *(const u16x8*)&hs[8];
    *(u16x8*)&xl[base] = *(const u16x8*)&ls[0];
    *(u16x8*)&xl[base + 8] = *(const u16x8*)&ls[8];
  }
}

// ------------------------------------------------- MFMA GEMM + argmin ------
// scores[t, k] = ||e_k||^2 - (2 x . e_k);  per-block per-row argmin over its
// 128-col tile -> cand arrays [NK/BN][NBT].
__global__ __launch_bounds__(256) void argmin_gemm_kernel(
    const u16* __restrict__ xh, const u16* __restrict__ xl,
    const u16* __restrict__ eh2, const u16* __restrict__ el2,
    const float* __restrict__ enorm, float* __restrict__ cand_v,
    int* __restrict__ cand_i) {
  __shared__ u16 As[BM][BK];
  __shared__ u16 Bs[BN][BK];
  __shared__ float cvs[2][BM];
  __shared__ int cis[2][BM];
  const int tid = threadIdx.x;
  const int w = tid >> 6, l = tid & 63;
  const int bt0 = blockIdx.x * BM, c0 = blockIdx.y * BN;
  const int wrow = w >> 1, wcol = w & 1;

  f32x4 acc[4][4];
#pragma unroll
  for (int m = 0; m < 4; ++m)
#pragma unroll
    for (int n = 0; n < 4; ++n) acc[m][n] = (f32x4)0.f;

  for (int kt = 0; kt < KP / BK; ++kt) {
    const int k0 = kt * BK;
    // region mapping: k<512: xh*eh2 ; 512..1023: xh*el2 ; 1024..1535: xl*eh2
    const u16* sA = (k0 < 1024 ? xh : xl) + (k0 & 511);
    const u16* sB = (((k0 & 1023) < 512) ? eh2 : el2) + (k0 & 511);
    __syncthreads();
#pragma unroll
    for (int i = 0; i < 4; ++i) {
      const int row = w * 32 + i * 8 + (l >> 3);
      const int coff = (l & 7) * 8;
      gload16(&As[w * 32 + i * 8][0], &sA[(size_t)(bt0 + row) * ND + coff]);
      gload16(&Bs[w * 32 + i * 8][0], &sB[(size_t)(c0 + row) * ND + coff]);
    }
    __syncthreads();
#pragma unroll
    for (int kk = 0; kk < BK; kk += 32) {
      short8 af[4], bfr[4];
#pragma unroll
      for (int m = 0; m < 4; ++m)
        af[m] = *(const short8*)&As[wrow * 64 + m * 16 + (l & 15)]
                                   [kk + (l >> 4) * 8];
#pragma unroll
      for (int n = 0; n < 4; ++n)
        bfr[n] = *(const short8*)&Bs[wcol * 64 + n * 16 + (l & 15)]
                                    [kk + (l >> 4) * 8];
#pragma unroll
      for (int m = 0; m < 4; ++m)
#pragma unroll
        for (int n = 0; n < 4; ++n)
          acc[m][n] = __builtin_amdgcn_mfma_f32_16x16x32_bf16(
              af[m], bfr[n], acc[m][n], 0, 0, 0);
    }
  }

  // ---- epilogue: per-row argmin over this block's 128 cols ----
  float bv[4][4];
  int bi[4][4];
#pragma unroll
  for (int m = 0; m < 4; ++m)
#pragma unroll
    for (int q = 0; q < 4; ++q) {
      bv[m][q] = INFINITY;
      bi[m][q] = 0;
    }
#pragma unroll
  for (int n = 0; n < 4; ++n) {
    const int col = c0 + wcol * 64 + n * 16 + (l & 15);
    const float en = enorm[col];
#pragma unroll
    for (int m = 0; m < 4; ++m)
#pragma unroll
      for (int q = 0; q < 4; ++q) {
        const float s = en - acc[m][n][q];
        if (s < bv[m][q]) {  // ascending col -> first-min tie-break
          bv[m][q] = s;
          bi[m][q] = col;
        }
      }
  }
#pragma unroll
  for (int msk = 1; msk < 16; msk <<= 1) {
#pragma unroll
    for (int m = 0; m < 4; ++m)
#pragma unroll
      for (int q = 0; q < 4; ++q) {
        const float ov = __shfl_xor(bv[m][q], msk);
        const int oi = __shfl_xor(bi[m][q], msk);
        if (ov < bv[m][q] || (ov == bv[m][q] && oi < bi[m][q])) {
          bv[m][q] = ov;
          bi[m][q] = oi;
        }
      }
  }
  if ((l & 15) == 0) {
    const int g = l >> 4;
#pragma unroll
    for (int m = 0; m < 4; ++m)
#pragma unroll
      for (int q = 0; q < 4; ++q) {
        const int rl = wrow * 64 + m * 16 + g * 4 + q;
        cvs[wcol][rl] = bv[m][q];
        cis[wcol][rl] = bi[m][q];
      }
  }
  __syncthreads();
  if (tid < BM) {
    const float v0 = cvs[0][tid], v1 = cvs[1][tid];
    const int j0 = cis[0][tid], j1 = cis[1][tid];
    const bool t1 = v1 < v0;  // half-1 cols all larger; tie keeps half-0
    cand_v[(size_t)blockIdx.y * NBT + bt0 + tid] = t1 ? v1 : v0;
    cand_i[(size_t)blockIdx.y * NBT + bt0 + tid] = t1 ? j1 : j0;
  }
}

// ----------------------------------- combine + exact fp32 top-2 rescore ----
__global__ __launch_bounds__(256) void combine_rescore_kernel(
    const float* __restrict__ cand_v, const int* __restrict__ cand_i,
    const float* __restrict__ x, const float* __restrict__ emb,
    const float* __restrict__ enorm, int* __restrict__ idx_ws,
    float* __restrict__ idxf) {
  const int r = blockIdx.x * 256 + threadIdx.x;
  float v1 = INFINITY, v2 = INFINITY;
  int i1 = 0, i2 = 0;
#pragma unroll
  for (int nt = 0; nt < NK / BN; ++nt) {  // ascending nt -> ascending index
    const float v = cand_v[(size_t)nt * NBT + r];
    const int i = cand_i[(size_t)nt * NBT + r];
    if (v < v1) {
      v2 = v1;
      i2 = i1;
      v1 = v;
      i1 = i;
    } else if (v < v2) {
      v2 = v;
      i2 = i;
    }
  }
  const int b = r >> 12, t = r & (NT - 1);
  const float* xb = x + (size_t)b * ND * NT + t;
  const float* e1 = emb + (size_t)i1 * ND;
  const float* e2 = emb + (size_t)i2 * ND;
  float d1 = 0.f, d2 = 0.f;
#pragma unroll 8
  for (int d = 0; d < ND; ++d) {
    const float xv = xb[(size_t)d * NT];
    d1 += xv * e1[d];
    d2 += xv * e2[d];
  }
  const float s1 = enorm[i1] - 2.f * d1;
  const float s2 = enorm[i2] - 2.f * d2;
  const int best = (s2 < s1 || (s2 == s1 && i2 < i1)) ? i2 : i1;
  idx_ws[r] = best;
  idxf[r] = (float)best;
}

// ------------------------------------------------------- gather + loss -----
__global__ __launch_bounds__(256) void gather_kernel(
    const float* __restrict__ x, const float* __restrict__ emb,
    const int* __restrict__ idx_ws, float* __restrict__ vals_out,
    float* __restrict__ partials) {
  __shared__ float tile[64][65];
  const int tid = threadIdx.x;
  const int bt0 = blockIdx.x * 64;
  const int d0 = blockIdx.y * 64;
  const int b = bt0 / NT;
  const int t0 = bt0 % NT;
  {
    const int dd4 = (tid & 15) * 4;
    const int ttb = tid >> 4;
#pragma unroll
    for (int p = 0; p < 4; ++p) {
      const int tt = ttb + p * 16;
      const int r = idx_ws[bt0 + tt];
      float4 v = *(const float4*)&emb[(size_t)r * ND + d0 + dd4];
      tile[tt][dd4 + 0] = v.x;
      tile[tt][dd4 + 1] = v.y;
      tile[tt][dd4 + 2] = v.z;
      tile[tt][dd4 + 3] = v.w;
    }
  }
  __syncthreads();
  float lsum = 0.f;
  {
    const int tt4 = (tid & 15) * 4;
    const int ddb = tid >> 4;
#pragma unroll
    for (int p = 0; p < 4; ++p) {
      const int dd = ddb + p * 16;
      float4 v;
      v.x = tile[tt4 + 0][dd];
      v.y = tile[tt4 + 1][dd];
      v.z = tile[tt4 + 2][dd];
      v.w = tile[tt4 + 3][dd];
      const size_t o = (size_t)b * ND * NT + (size_t)(d0 + dd) * NT + t0 + tt4;
      const float4 xr = *(const float4*)&x[o];
      *(float4*)&vals_out[o] = v;
      const float e0 = xr.x - v.x, e1 = xr.y - v.y;
      const float e2 = xr.z - v.z, e3 = xr.w - v.w;
      lsum += e0 * e0 + e1 * e1 + e2 * e2 + e3 * e3;
    }
  }
#pragma unroll
  for (int m = 32; m; m >>= 1) lsum += __shfl_xor(lsum, m);
  __shared__ float wsum[4];
  if ((tid & 63) == 0) wsum[tid >> 6] = lsum;
  __syncthreads();
  if (tid == 0)
    partials[blockIdx.y * gridDim.x + blockIdx.x] =
        wsum[0] + wsum[1] + wsum[2] + wsum[3];
}

__global__ void loss_kernel(const float* __restrict__ partials, int n,
                            float* __restrict__ out) {
  float s = 0.f;
  for (int i = threadIdx.x; i < n; i += 256) s += partials[i];
#pragma unroll
  for (int m = 32; m; m >>= 1) s += __shfl_xor(s, m);
  __shared__ float wsum[4];
  if ((threadIdx.x & 63) == 0) wsum[threadIdx.x >> 6] = s;
  __syncthreads();
  if (threadIdx.x == 0)
    out[0] = 2.0f * (wsum[0] + wsum[1] + wsum[2] + wsum[3]) /
             (float)((size_t)NB * ND * NT);
}

// --------------------------------------------------------------- launch ----
extern "C" void kernel_launch(void* const* d_in, const int* in_sizes, int n_in,
                              void* d_out, int out_size, void* d_ws,
                              size_t ws_size, hipStream_t stream) {
  const float* x = (const float*)d_in[0];
  const float* emb = (const float*)d_in[1];
  float* out = (float*)d_out;
  float* vals_out = out;                         // [B, D, T]
  float* idxf_out = out + (size_t)NB * ND * NT;  // [B, T] as float
  float* loss_out = idxf_out + NBT;              // scalar

  u16* xh = (u16*)d_ws;                          // NBT*ND
  u16* xl = xh + (size_t)NBT * ND;               // NBT*ND
  u16* eh2 = xl + (size_t)NBT * ND;              // NK*ND
  u16* el2 = eh2 + (size_t)NK * ND;              // NK*ND
  float* enorm = (float*)(el2 + (size_t)NK * ND);  // NK
  float* cand_v = enorm + NK;                    // (NK/BN)*NBT
  int* cand_i = (int*)(cand_v + (size_t)(NK / BN) * NBT);
  int* idx_ws = cand_i + (size_t)(NK / BN) * NBT;  // NBT
  float* partials = (float*)(idx_ws + NBT);        // 2048

  conv_e_kernel<<<NK / 4, 256, 0, stream>>>(emb, eh2, el2, enorm);
  conv_x_kernel<<<dim3(NBT / 64, ND / 64), 256, 0, stream>>>(x, xh, xl);
  argmin_gemm_kernel<<<dim3(NBT / BM, NK / BN), 256, 0, stream>>>(
      xh, xl, eh2, el2, enorm, cand_v, cand_i);
  combine_rescore_kernel<<<NBT / 256, 256, 0, stream>>>(cand_v, cand_i, x, emb,
                                                        enorm, idx_ws,
                                                        idxf_out);
  gather_kernel<<<dim3(NBT / 64, ND / 64), 256, 0, stream>>>(x, emb, idx_ws,
                                                             vals_out,
                                                             partials);
  loss_kernel<<<1, 256, 0, stream>>>(partials, 2048, loss_out);
}

// Round 3
// 295.756 us; speedup vs baseline: 3.0816x; 1.4341x over previous
//
#include <hip/hip_runtime.h>
#include <cstddef>
#include <cstdint>

#define NB 4
#define ND 512
#define NT 4096
#define NK 4096
#define NBT (NB * NT)
#define KP 1536   // augmented K' = 3*ND: xh*eh2 | xh*el2 | xl*eh2
#define BK 64
#define NKT (KP / BK)  // 24 K-tiles
#define CT (NK / 256)  // 16 candidate tiles

typedef __attribute__((ext_vector_type(4))) float f32x4;
typedef __attribute__((ext_vector_type(8))) short short8;
typedef __attribute__((ext_vector_type(8))) unsigned short u16x8;
typedef unsigned short u16;

__device__ inline u16 f2bf_rn(float f) {
  unsigned u = __float_as_uint(f);
  return (u16)((u + 0x7FFFu + ((u >> 16) & 1u)) >> 16);
}
__device__ inline float bf2f(u16 h) {
  return __uint_as_float(((unsigned)h) << 16);
}
__device__ inline void gload16(void* lds_p, const void* g) {
  __builtin_amdgcn_global_load_lds(
      (const __attribute__((address_space(1))) unsigned int*)g,
      (__attribute__((address_space(3))) unsigned int*)lds_p, 16, 0, 0);
}

// ---------------------------------------------------- e conversion + norm --
__global__ void conv_e_kernel(const float* __restrict__ emb,
                              u16* __restrict__ eh2, u16* __restrict__ el2,
                              float* __restrict__ enorm) {
  int row = blockIdx.x * 4 + (threadIdx.x >> 6);
  int l = threadIdx.x & 63;
  const float* e = emb + (size_t)row * ND;
  float s = 0.f;
#pragma unroll
  for (int i = 0; i < ND / 64; ++i) {
    int idx = l + i * 64;
    float v = e[idx];
    s += v * v;
    float v2 = 2.f * v;
    u16 h = f2bf_rn(v2);
    u16 lo = f2bf_rn(v2 - bf2f(h));
    eh2[(size_t)row * ND + idx] = h;
    el2[(size_t)row * ND + idx] = lo;
  }
#pragma unroll
  for (int m = 32; m; m >>= 1) s += __shfl_xor(s, m);
  if (l == 0) enorm[row] = s;
}

// ------------------------------------------- x conversion (+ transpose) ----
__global__ __launch_bounds__(256) void conv_x_kernel(const float* __restrict__ x,
                                                     u16* __restrict__ xh,
                                                     u16* __restrict__ xl) {
  __shared__ float tile[64][68];
  const int tid = threadIdx.x;
  const int bt0 = blockIdx.x * 64, d0 = blockIdx.y * 64;
  const int b = bt0 / NT, t0 = bt0 % NT;
  const float* xb = x + (size_t)b * ND * NT;
  {
    const int tt4 = (tid & 15) * 4, ddb = tid >> 4;
#pragma unroll
    for (int p = 0; p < 4; ++p) {
      const int dd = ddb + p * 16;
      float4 v = *(const float4*)&xb[(size_t)(d0 + dd) * NT + t0 + tt4];
      *(float4*)&tile[dd][tt4] = v;
    }
  }
  __syncthreads();
  {
    const int t_loc = tid >> 2, dg = tid & 3;
    u16 hs[16], ls[16];
#pragma unroll
    for (int j = 0; j < 16; ++j) {
      float f = tile[dg * 16 + j][t_loc];
      u16 h = f2bf_rn(f);
      hs[j] = h;
      ls[j] = f2bf_rn(f - bf2f(h));
    }
    const size_t base = (size_t)(bt0 + t_loc) * ND + d0 + dg * 16;
    *(u16x8*)&xh[base] = *(const u16x8*)&hs[0];
    *(u16x8*)&xh[base + 8] = *(const u16x8*)&hs[8];
    *(u16x8*)&xl[base] = *(const u16x8*)&ls[0];
    *(u16x8*)&xl[base + 8] = *(const u16x8*)&ls[8];
  }
}

// ------------------------------------------------- 8-phase GEMM + argmin ---
// 256x256 tile, 8 waves (2M x 4N), BK=64, LDS 128 KiB double-buffered,
// st-swizzle via pre-swizzled global source (T2) + counted vmcnt (T3/T4)
// + setprio (T5). Epilogue: per-row argmin over the block's 256 cols.
__device__ __forceinline__ void stage_chunk(
    u16 (&lds)[2][2][256][64], int bn, int j, int tn, const u16* xh,
    const u16* xl, const u16* eh2, const u16* el2, int bt0, int c0g, int w,
    int l) {
  if (tn >= NKT) return;
  const int k0s = tn * BK;
  const int kA = k0s & 511;
  const bool isA = (j == 0) || (j == 3);
  const u16* src;
  if (isA)
    src = (k0s < 1024 ? xh : xl);
  else
    src = (((k0s & 1023) < 512) ? eh2 : el2);
#pragma unroll
  for (int i = 0; i < 2; ++i) {
    const int s = w + i * 8;        // span 0..15 (8 LDS rows each)
    const int rl0 = s * 8;          // chunk-row of lane group 0
    const int rl = rl0 + (l >> 3);  // this lane's chunk-row
    const int slot = l & 7;         // 16B slot within row
    int rowL, rowL0, grow;
    if (isA) {  // chunk rows: j==0 -> {0-63,128-191}; j==3 -> +64
      rowL = ((rl & 63) | ((rl & 64) << 1)) + (j == 3 ? 64 : 0);
      rowL0 = ((rl0 & 63) | ((rl0 & 64) << 1)) + (j == 3 ? 64 : 0);
      grow = bt0 + rowL;
    } else {  // chunk rows: j==1 -> {wn*64+[0,32)}; j==2 -> +32
      rowL = (j == 2 ? 32 : 0) + (rl & 31) + ((rl >> 5) << 6);
      rowL0 = (j == 2 ? 32 : 0) + (rl0 & 31) + ((rl0 >> 5) << 6);
      grow = c0g + rowL;
    }
    const int gslot = slot ^ (rowL & 7);  // pre-swizzled global source
    gload16(&lds[bn][isA ? 0 : 1][rowL0][0],
            &src[(size_t)grow * ND + kA + gslot * 8]);
  }
}

__global__ __launch_bounds__(512, 2) void argmin_gemm_kernel(
    const u16* __restrict__ xh, const u16* __restrict__ xl,
    const u16* __restrict__ eh2, const u16* __restrict__ el2,
    const float* __restrict__ enorm, float* __restrict__ cand_v,
    int* __restrict__ cand_i) {
  __shared__ u16 lds[2][2][256][64];  // [buf][A/B][row][k] = 128 KiB
  const int tid = threadIdx.x;
  const int w = tid >> 6, l = tid & 63;
  const int l15 = l & 15, l4 = l >> 4;
  const int wm = w >> 2, wn = w & 3;
  // XCD-aware bijective swizzle: nwg=1024, 128 blocks per XCD chunk.
  const int id = blockIdx.x;
  const int id_sw = (id & 7) * 128 + (id >> 3);
  const int bx = id_sw & 63, by = id_sw >> 6;
  const int bt0 = bx * 256, c0g = by * 256;

  f32x4 acc[2][4][2][2];  // [qm][m][qn][n]
#pragma unroll
  for (int qm = 0; qm < 2; ++qm)
#pragma unroll
    for (int m = 0; m < 4; ++m)
#pragma unroll
      for (int qn = 0; qn < 2; ++qn)
#pragma unroll
        for (int n = 0; n < 2; ++n) acc[qm][m][qn][n] = (f32x4)0.f;

  short8 aF[4][2], bF0[2][2], bF1[2][2];

#define DS_A(QM)                                                         \
  _Pragma("unroll") for (int m = 0; m < 4; ++m) {                        \
    _Pragma("unroll") for (int kf = 0; kf < 2; ++kf) {                   \
      const int row = wm * 128 + (QM) * 64 + m * 16 + l15;               \
      const int slot = (kf * 4 + l4) ^ (row & 7);                        \
      aF[m][kf] = *(const short8*)&lds[cur][0][row][slot * 8];           \
    }                                                                    \
  }
#define DS_B(QN, BF)                                                     \
  _Pragma("unroll") for (int n = 0; n < 2; ++n) {                        \
    _Pragma("unroll") for (int kf = 0; kf < 2; ++kf) {                   \
      const int row = wn * 64 + (QN) * 32 + n * 16 + l15;                \
      const int slot = (kf * 4 + l4) ^ (row & 7);                        \
      BF[n][kf] = *(const short8*)&lds[cur][1][row][slot * 8];           \
    }                                                                    \
  }
#define MM(QM, QN, BF)                                                   \
  __builtin_amdgcn_s_setprio(1);                                         \
  _Pragma("unroll") for (int m = 0; m < 4; ++m) {                        \
    _Pragma("unroll") for (int n = 0; n < 2; ++n) {                      \
      _Pragma("unroll") for (int kf = 0; kf < 2; ++kf) {                 \
        acc[QM][m][QN][n] = __builtin_amdgcn_mfma_f32_16x16x32_bf16(     \
            aF[m][kf], BF[n][kf], acc[QM][m][QN][n], 0, 0, 0);           \
      }                                                                  \
    }                                                                    \
  }                                                                      \
  __builtin_amdgcn_s_setprio(0);
#define BAR __builtin_amdgcn_s_barrier()
#define LGK                                              \
  asm volatile("s_waitcnt lgkmcnt(0)" ::: "memory");     \
  __builtin_amdgcn_sched_barrier(0)

  // prologue: stage all 4 chunks of tile 0 into buf 0; publish chunks 0,1
  stage_chunk(lds, 0, 0, 0, xh, xl, eh2, el2, bt0, c0g, w, l);
  stage_chunk(lds, 0, 1, 0, xh, xl, eh2, el2, bt0, c0g, w, l);
  stage_chunk(lds, 0, 2, 0, xh, xl, eh2, el2, bt0, c0g, w, l);
  stage_chunk(lds, 0, 3, 0, xh, xl, eh2, el2, bt0, c0g, w, l);
  asm volatile("s_waitcnt vmcnt(4)" ::: "memory");
  BAR;

  for (int t = 0; t < NKT; ++t) {
    const int cur = t & 1;
    const int nb = cur ^ 1;
    const int tn = t + 1;
    // P0: needs chunks 0(A qm0),1(B qn0) of tile t
    DS_A(0);
    DS_B(0, bF0);
    stage_chunk(lds, nb, 0, tn, xh, xl, eh2, el2, bt0, c0g, w, l);
    BAR;
    LGK;
    MM(0, 0, bF0);
    asm volatile("s_waitcnt vmcnt(4)" ::: "memory");
    BAR;
    // P1: needs chunk 2(B qn1)
    DS_B(1, bF1);
    stage_chunk(lds, nb, 1, tn, xh, xl, eh2, el2, bt0, c0g, w, l);
    BAR;
    LGK;
    MM(0, 1, bF1);
    asm volatile("s_waitcnt vmcnt(4)" ::: "memory");
    BAR;
    // P2: needs chunk 3(A qm1); reuses bF0
    DS_A(1);
    stage_chunk(lds, nb, 2, tn, xh, xl, eh2, el2, bt0, c0g, w, l);
    BAR;
    LGK;
    MM(1, 0, bF0);
    asm volatile("s_waitcnt vmcnt(6)" ::: "memory");
    BAR;
    // P3: register-only; reuses aF(qm1), bF1
    stage_chunk(lds, nb, 3, tn, xh, xl, eh2, el2, bt0, c0g, w, l);
    BAR;
    LGK;
    MM(1, 1, bF1);
    asm volatile("s_waitcnt vmcnt(4)" ::: "memory");
    BAR;
  }
#undef DS_A
#undef DS_B
#undef MM
#undef BAR
#undef LGK

  // ---- epilogue: per-row argmin over this block's 256 cols ----
  __syncthreads();  // full drain; LDS reused below
  float* cvs = (float*)&lds[0][0][0][0];  // [4][256]
  int* cis = (int*)(cvs + 4 * 256);       // [4][256]

  float bv[2][4][4];
  int bi[2][4][4];
#pragma unroll
  for (int qm = 0; qm < 2; ++qm)
#pragma unroll
    for (int m = 0; m < 4; ++m)
#pragma unroll
      for (int q = 0; q < 4; ++q) {
        bv[qm][m][q] = INFINITY;
        bi[qm][m][q] = 0;
      }
#pragma unroll
  for (int qn = 0; qn < 2; ++qn)  // ascending col order -> first-min ties
#pragma unroll
    for (int n = 0; n < 2; ++n) {
      const int col = c0g + wn * 64 + qn * 32 + n * 16 + l15;
      const float en = enorm[col];
#pragma unroll
      for (int qm = 0; qm < 2; ++qm)
#pragma unroll
        for (int m = 0; m < 4; ++m)
#pragma unroll
          for (int q = 0; q < 4; ++q) {
            const float s = en - acc[qm][m][qn][n][q];
            if (s < bv[qm][m][q]) {
              bv[qm][m][q] = s;
              bi[qm][m][q] = col;
            }
          }
    }
#pragma unroll
  for (int msk = 1; msk < 16; msk <<= 1) {
#pragma unroll
    for (int qm = 0; qm < 2; ++qm)
#pragma unroll
      for (int m = 0; m < 4; ++m)
#pragma unroll
        for (int q = 0; q < 4; ++q) {
          const float ov = __shfl_xor(bv[qm][m][q], msk);
          const int oi = __shfl_xor(bi[qm][m][q], msk);
          if (ov < bv[qm][m][q] || (ov == bv[qm][m][q] && oi < bi[qm][m][q])) {
            bv[qm][m][q] = ov;
            bi[qm][m][q] = oi;
          }
        }
  }
  if (l15 == 0) {
#pragma unroll
    for (int qm = 0; qm < 2; ++qm)
#pragma unroll
      for (int m = 0; m < 4; ++m)
#pragma unroll
        for (int q = 0; q < 4; ++q) {
          const int row = wm * 128 + qm * 64 + m * 16 + l4 * 4 + q;
          cvs[wn * 256 + row] = bv[qm][m][q];
          cis[wn * 256 + row] = bi[qm][m][q];
        }
  }
  __syncthreads();
  if (tid < 256) {
    float v = cvs[tid];
    int bidx = cis[tid];
#pragma unroll
    for (int q = 1; q < 4; ++q) {  // ascending wn -> ascending cols
      const float ov = cvs[q * 256 + tid];
      const int oi = cis[q * 256 + tid];
      if (ov < v) {
        v = ov;
        bidx = oi;
      }
    }
    cand_v[(size_t)by * NBT + bt0 + tid] = v;
    cand_i[(size_t)by * NBT + bt0 + tid] = bidx;
  }
}

// ----------------------------------- combine + exact fp32 top-2 rescore ----
__global__ __launch_bounds__(256) void combine_rescore_kernel(
    const float* __restrict__ cand_v, const int* __restrict__ cand_i,
    const float* __restrict__ x, const float* __restrict__ emb,
    const float* __restrict__ enorm, int* __restrict__ idx_ws,
    float* __restrict__ idxf) {
  const int r = blockIdx.x * 256 + threadIdx.x;
  float v1 = INFINITY, v2 = INFINITY;
  int i1 = 0, i2 = 0;
#pragma unroll
  for (int nt = 0; nt < CT; ++nt) {  // ascending nt -> ascending index
    const float v = cand_v[(size_t)nt * NBT + r];
    const int i = cand_i[(size_t)nt * NBT + r];
    if (v < v1) {
      v2 = v1;
      i2 = i1;
      v1 = v;
      i1 = i;
    } else if (v < v2) {
      v2 = v;
      i2 = i;
    }
  }
  const int b = r >> 12, t = r & (NT - 1);
  const float* xb = x + (size_t)b * ND * NT + t;
  const float* e1 = emb + (size_t)i1 * ND;
  const float* e2 = emb + (size_t)i2 * ND;
  float d1 = 0.f, d2 = 0.f;
#pragma unroll 8
  for (int d = 0; d < ND; ++d) {
    const float xv = xb[(size_t)d * NT];
    d1 += xv * e1[d];
    d2 += xv * e2[d];
  }
  const float s1 = enorm[i1] - 2.f * d1;
  const float s2 = enorm[i2] - 2.f * d2;
  const int best = (s2 < s1 || (s2 == s1 && i2 < i1)) ? i2 : i1;
  idx_ws[r] = best;
  idxf[r] = (float)best;
}

// ------------------------------------------------------- gather + loss -----
__global__ __launch_bounds__(256) void gather_kernel(
    const float* __restrict__ x, const float* __restrict__ emb,
    const int* __restrict__ idx_ws, float* __restrict__ vals_out,
    float* __restrict__ partials) {
  __shared__ float tile[64][65];
  const int tid = threadIdx.x;
  const int bt0 = blockIdx.x * 64;
  const int d0 = blockIdx.y * 64;
  const int b = bt0 / NT;
  const int t0 = bt0 % NT;
  {
    const int dd4 = (tid & 15) * 4;
    const int ttb = tid >> 4;
#pragma unroll
    for (int p = 0; p < 4; ++p) {
      const int tt = ttb + p * 16;
      const int r = idx_ws[bt0 + tt];
      float4 v = *(const float4*)&emb[(size_t)r * ND + d0 + dd4];
      tile[tt][dd4 + 0] = v.x;
      tile[tt][dd4 + 1] = v.y;
      tile[tt][dd4 + 2] = v.z;
      tile[tt][dd4 + 3] = v.w;
    }
  }
  __syncthreads();
  float lsum = 0.f;
  {
    const int tt4 = (tid & 15) * 4;
    const int ddb = tid >> 4;
#pragma unroll
    for (int p = 0; p < 4; ++p) {
      const int dd = ddb + p * 16;
      float4 v;
      v.x = tile[tt4 + 0][dd];
      v.y = tile[tt4 + 1][dd];
      v.z = tile[tt4 + 2][dd];
      v.w = tile[tt4 + 3][dd];
      const size_t o = (size_t)b * ND * NT + (size_t)(d0 + dd) * NT + t0 + tt4;
      const float4 xr = *(const float4*)&x[o];
      *(float4*)&vals_out[o] = v;
      const float e0 = xr.x - v.x, e1 = xr.y - v.y;
      const float e2 = xr.z - v.z, e3 = xr.w - v.w;
      lsum += e0 * e0 + e1 * e1 + e2 * e2 + e3 * e3;
    }
  }
#pragma unroll
  for (int m = 32; m; m >>= 1) lsum += __shfl_xor(lsum, m);
  __shared__ float wsum[4];
  if ((tid & 63) == 0) wsum[tid >> 6] = lsum;
  __syncthreads();
  if (tid == 0)
    partials[blockIdx.y * gridDim.x + blockIdx.x] =
        wsum[0] + wsum[1] + wsum[2] + wsum[3];
}

__global__ void loss_kernel(const float* __restrict__ partials, int n,
                            float* __restrict__ out) {
  float s = 0.f;
  for (int i = threadIdx.x; i < n; i += 256) s += partials[i];
#pragma unroll
  for (int m = 32; m; m >>= 1) s += __shfl_xor(s, m);
  __shared__ float wsum[4];
  if ((threadIdx.x & 63) == 0) wsum[threadIdx.x >> 6] = s;
  __syncthreads();
  if (threadIdx.x == 0)
    out[0] = 2.0f * (wsum[0] + wsum[1] + wsum[2] + wsum[3]) /
             (float)((size_t)NB * ND * NT);
}

// --------------------------------------------------------------- launch ----
extern "C" void kernel_launch(void* const* d_in, const int* in_sizes, int n_in,
                              void* d_out, int out_size, void* d_ws,
                              size_t ws_size, hipStream_t stream) {
  const float* x = (const float*)d_in[0];
  const float* emb = (const float*)d_in[1];
  float* out = (float*)d_out;
  float* vals_out = out;                         // [B, D, T]
  float* idxf_out = out + (size_t)NB * ND * NT;  // [B, T] as float
  float* loss_out = idxf_out + NBT;              // scalar

  u16* xh = (u16*)d_ws;                            // NBT*ND
  u16* xl = xh + (size_t)NBT * ND;                 // NBT*ND
  u16* eh2 = xl + (size_t)NBT * ND;                // NK*ND
  u16* el2 = eh2 + (size_t)NK * ND;                // NK*ND
  float* enorm = (float*)(el2 + (size_t)NK * ND);  // NK
  float* cand_v = enorm + NK;                      // CT * NBT
  int* cand_i = (int*)(cand_v + (size_t)CT * NBT);
  int* idx_ws = cand_i + (size_t)CT * NBT;  // NBT
  float* partials = (float*)(idx_ws + NBT); // 2048

  conv_e_kernel<<<NK / 4, 256, 0, stream>>>(emb, eh2, el2, enorm);
  conv_x_kernel<<<dim3(NBT / 64, ND / 64), 256, 0, stream>>>(x, xh, xl);
  argmin_gemm_kernel<<<1024, 512, 0, stream>>>(xh, xl, eh2, el2, enorm, cand_v,
                                               cand_i);
  combine_rescore_kernel<<<NBT / 256, 256, 0, stream>>>(cand_v, cand_i, x, emb,
                                                        enorm, idx_ws,
                                                        idxf_out);
  gather_kernel<<<dim3(NBT / 64, ND / 64), 256, 0, stream>>>(x, emb, idx_ws,
                                                             vals_out,
                                                             partials);
  loss_kernel<<<1, 256, 0, stream>>>(partials, 2048, loss_out);
}